// Round 13
// baseline (403.787 us; speedup 1.0000x reference)
//
#include <hip/hip_runtime.h>

#define KK 27
#define INC 32
#define PC 64

typedef __attribute__((ext_vector_type(8))) short v8s;
typedef __attribute__((ext_vector_type(4))) float f32x4;

static __device__ __forceinline__ float b2f(ushort u) {
  union { float f; unsigned int i; } x; x.i = ((unsigned int)u) << 16; return x.f;
}
static __device__ __forceinline__ ushort f2b(float f) {
  union { float f; unsigned int i; } x; x.f = f;
  unsigned int u = x.i;
  unsigned int r = (u + 0x7FFFu + ((u >> 16) & 1u)) >> 16;
  return (ushort)r;
}

// ---------------- Kernel 1: x=relu(xf@Wt+bt) (LDS only), v=relu(x@Wv+bv) [bf16],
// zc16[n] = one 64B line: [cx,cy,cz,pad (ushort)] + z[n][k]=dot(x,Wq_k) bf16 x27
__global__ __launch_bounds__(256) void k_prep(
    const float* __restrict__ xf, const float* __restrict__ Wt, const float* __restrict__ bt,
    const float* __restrict__ Wv, const float* __restrict__ bv,
    const float* __restrict__ Wq, const int* __restrict__ coords,
    ushort* __restrict__ v, ushort* __restrict__ zc16, int N)
{
  int tid = threadIdx.x, lane = tid & 63, w = tid >> 6;
  int vbase = blockIdx.x * 16;
  __shared__ float xin[16][32];
  __shared__ float xs[16][64];
  if (tid < 128) {
    int r = tid >> 3, c4 = tid & 7;
    int n = vbase + r;
    float4 d = make_float4(0.f, 0.f, 0.f, 0.f);
    if (n < N) d = *(const float4*)(xf + (size_t)n * INC + c4 * 4);
    *(float4*)(&xin[r][c4 * 4]) = d;
  }
  __syncthreads();
  float a0 = bt[lane], a1 = a0, a2 = a0, a3 = a0;
  #pragma unroll
  for (int i = 0; i < INC; ++i) {
    float wt = Wt[i * PC + lane];
    a0 += xin[w * 4 + 0][i] * wt; a1 += xin[w * 4 + 1][i] * wt;
    a2 += xin[w * 4 + 2][i] * wt; a3 += xin[w * 4 + 3][i] * wt;
  }
  a0 = fmaxf(a0, 0.f); a1 = fmaxf(a1, 0.f); a2 = fmaxf(a2, 0.f); a3 = fmaxf(a3, 0.f);
  xs[w * 4 + 0][lane] = a0; xs[w * 4 + 1][lane] = a1;
  xs[w * 4 + 2][lane] = a2; xs[w * 4 + 3][lane] = a3;
  __syncthreads();
  // v = relu(x@Wv+bv)
  float v0 = bv[lane], v1 = v0, v2 = v0, v3 = v0;
  #pragma unroll
  for (int i = 0; i < PC; ++i) {
    float wv = Wv[i * PC + lane];
    v0 += xs[w * 4 + 0][i] * wv; v1 += xs[w * 4 + 1][i] * wv;
    v2 += xs[w * 4 + 2][i] * wv; v3 += xs[w * 4 + 3][i] * wv;
  }
  {
    int n0 = vbase + w * 4;
    if (n0 + 0 < N) v[(size_t)(n0 + 0) * PC + lane] = f2b(fmaxf(v0, 0.f));
    if (n0 + 1 < N) v[(size_t)(n0 + 1) * PC + lane] = f2b(fmaxf(v1, 0.f));
    if (n0 + 2 < N) v[(size_t)(n0 + 2) * PC + lane] = f2b(fmaxf(v2, 0.f));
    if (n0 + 3 < N) v[(size_t)(n0 + 3) * PC + lane] = f2b(fmaxf(v3, 0.f));
  }
  // z-tail: voxel g = tid>>4, lane-in-group l = tid&15; plain dot64 per (g,k)
  {
    int g = tid >> 4, l = tid & 15;
    int nz = vbase + g;
    if (nz < N) {
      ushort* row = zc16 + (size_t)nz * 32;
      #pragma unroll
      for (int h = 0; h < 2; ++h) {
        int k = l + h * 16;
        if (k < KK) {
          float zv = 0.f;
          #pragma unroll
          for (int c4 = 0; c4 < 16; ++c4) {
            float4 xv4 = *(const float4*)(&xs[g][c4 * 4]);
            float4 wq4 = *(const float4*)(Wq + k * PC + c4 * 4);
            zv += xv4.x * wq4.x + xv4.y * wq4.y + xv4.z * wq4.z + xv4.w * wq4.w;
          }
          row[4 + k] = f2b(zv);
        }
      }
      if (l == 0) {
        row[0] = (ushort)coords[nz * 3 + 0];
        row[1] = (ushort)coords[nz * 3 + 1];
        row[2] = (ushort)coords[nz * 3 + 2];
        row[3] = 0;
      }
    }
  }
}

// ---------------- Kernel 2: repack W_code -> Bp, and Wd -> Wdp (fused)
__global__ __launch_bounds__(256) void k_prepBD(
    const float* __restrict__ Wcode, const float* __restrict__ Wd,
    ushort* __restrict__ Bp, ushort* __restrict__ Wdp)
{
  int bid = blockIdx.x;
  if (bid < 1728) {
    int i = bid * 256 + threadIdx.x;   // 54*4*256*8 = 442368
    int j = i & 7;
    int col = (i >> 3) & 255;
    int kg = (i >> 11) & 3;
    int s = i >> 13;
    int k = s * 32 + kg * 8 + j;
    int m = col >> 6, d = col & 63;
    int knbr = k >> 6, c = k & 63;
    Bp[i] = f2b(Wcode[(((m * KK + knbr) * 64) + c) * 64 + d]);
  } else {
    int i = (bid - 1728) * 256 + threadIdx.x;   // 2048
    int col = i >> 5, k = i & 31;
    Wdp[i] = f2b(Wd[k * PC + col]);
  }
}

// ---------------- Kernel 3: gathered GEMM [64x1728]x[1728x256] with 1-line fused q:
// zc16 gather (coords+z in ONE 64B line) replaces x-row+coords gathers.
// R11/R9 GEMM core: 4x4 acc, 3-buffer ring, early commit, B-before-gather;
// per-lane m-sum epilogue + MFMA residual.
__global__ __launch_bounds__(256) void k_code(
    const ushort* __restrict__ v, const int* __restrict__ nbr_idx, const int* __restrict__ nbr_mask,
    const ushort* __restrict__ Bp, const ushort* __restrict__ zc16,
    const float* __restrict__ Wpos, const float* __restrict__ bpos,
    const float* __restrict__ Wq, const float* __restrict__ bq, const float* __restrict__ proj,
    const float* __restrict__ xf, const ushort* __restrict__ Wdp,
    const float* __restrict__ bd, const float* __restrict__ bcode,
    float* __restrict__ out, int N)
{
  const int tid = threadIdx.x;
  const int lane = tid & 63, w = tid >> 6;
  const int base = blockIdx.x * 64;

  __shared__ __align__(16) union SM {
    struct { ushort As[3][4096]; int jm[64][KK]; } g;   // GEMM phase (31.5 KB)
    struct { ushort xfb[64][40]; } e;                   // epilogue (5.1 KB)
  } sm;
  __shared__ __align__(16) float attnL[64][4];          // survives both phases (1 KB)

  for (int i = tid; i < 64 * KK; i += 256) {
    int r = i / KK, k = i % KK;
    int n = base + r;
    int val = -1;
    if (n < N && nbr_mask[(size_t)n * KK + k]) val = nbr_idx[(size_t)n * KK + k];
    sm.g.jm[r][k] = val;
  }

  const int r0 = tid >> 3, cc0 = tid & 7;
  const int r1 = r0 + 32;
  const int sc0 = cc0 ^ (r0 & 7), sc1 = cc0 ^ (r1 & 7);
  const int ch0 = cc0 * 8;

  __syncthreads();  // jm ready

  // own coords from zc16 line (guarded)
  const int n0g = base + r0, n1g = base + r1;
  int cx0 = 0, cy0 = 0, cz0 = 0, cx1 = 0, cy1 = 0, cz1 = 0;
  if (n0g < N) {
    uint2 cd = *(const uint2*)(zc16 + (size_t)n0g * 32);
    cx0 = (int)(cd.x & 0xffffu); cy0 = (int)(cd.x >> 16); cz0 = (int)(cd.y & 0xffffu);
  }
  if (n1g < N) {
    uint2 cd = *(const uint2*)(zc16 + (size_t)n1g * 32);
    cx1 = (int)(cd.x & 0xffffu); cy1 = (int)(cd.x >> 16); cz1 = (int)(cd.y & 0xffffu);
  }
  // pos-MLP weights for my 8 channels (loop-invariant)
  float wpr0[8], wpr1[8], wpr2[8], bpr[8];
  #pragma unroll
  for (int c = 0; c < 8; ++c) {
    wpr0[c] = Wpos[ch0 + c];
    wpr1[c] = Wpos[64 + ch0 + c];
    wpr2[c] = Wpos[128 + ch0 + c];
    bpr[c]  = bpos[ch0 + c];
  }
  const float bq0 = bq[0];
  float pj[4];
  #pragma unroll
  for (int m = 0; m < 4; ++m) pj[m] = proj[m] * 0.1f;

  // prologue: v(0) -> As[0]; v(1) -> R; q-data(0) -> regs
  uint4 R0 = make_uint4(0u,0u,0u,0u), R1 = R0;
  uint2 cj0, cj1;
  float zc0 = 0.f, zc1 = 0.f, mc0, mc1;
  {
    int ja = sm.g.jm[r0][0], jb = sm.g.jm[r1][0];
    uint4 p0 = make_uint4(0u, 0u, 0u, 0u), p1 = p0;
    if (ja >= 0) p0 = *(const uint4*)(v + (size_t)ja * PC + ch0);
    if (jb >= 0) p1 = *(const uint4*)(v + (size_t)jb * PC + ch0);
    int jc = sm.g.jm[r0][1], jd = sm.g.jm[r1][1];
    if (jc >= 0) R0 = *(const uint4*)(v + (size_t)jc * PC + ch0);
    if (jd >= 0) R1 = *(const uint4*)(v + (size_t)jd * PC + ch0);
    int jja = max(ja, 0), jjb = max(jb, 0);
    cj0 = *(const uint2*)(zc16 + (size_t)jja * 32);
    cj1 = *(const uint2*)(zc16 + (size_t)jjb * 32);
    if (cc0 == 0) {
      if (ja >= 0) zc0 = b2f(zc16[(size_t)ja * 32 + 4]);
      if (jb >= 0) zc1 = b2f(zc16[(size_t)jb * 32 + 4]);
    }
    mc0 = (ja >= 0) ? 1.f : 0.f; mc1 = (jb >= 0) ? 1.f : 0.f;
    *(uint4*)(&sm.g.As[0][r0 * 64 + sc0 * 8]) = p0;
    *(uint4*)(&sm.g.As[0][r1 * 64 + sc1 * 8]) = p1;
  }
  __syncthreads();

  f32x4 acc[4][4] = {};
  float qp0 = 0.f, qp1 = 0.f;
  // col = nt*64 + w*16 + (lane&15)  -> nt stride = 512 ushorts
  const ushort* bbase = Bp + (size_t)(lane >> 4) * 2048 + (size_t)((w << 4) + (lane & 15)) * 8;

  int cur = 0, nxb = 1;
  for (int kn = 0; kn < KK; ++kn) {
    // (1) B fragments — FIRST (MFMA's vmcnt stops here)
    v8s bf0[4], bf1[4];
    {
      const ushort* bb0 = bbase + (size_t)(8 * kn) * 2048;
      const ushort* bb1 = bb0 + 4 * 2048;
      #pragma unroll
      for (int nt = 0; nt < 4; ++nt) {
        bf0[nt] = *(const v8s*)(bb0 + nt * 512);
        bf1[nt] = *(const v8s*)(bb1 + nt * 512);
      }
    }
    // (1.5) Wq for this kn (L1-hot)
    float4 wqA = *(const float4*)(Wq + kn * PC + ch0);
    float4 wqB = *(const float4*)(Wq + kn * PC + ch0 + 4);
    // (2) EARLY COMMIT: v(kn+1), in flight since last iteration -> As[nxb]
    if (kn + 1 < KK) {
      *(uint4*)(&sm.g.As[nxb][r0 * 64 + sc0 * 8]) = R0;
      *(uint4*)(&sm.g.As[nxb][r1 * 64 + sc1 * 8]) = R1;
    }
    // (3) q-prefetch kn+1: ONE zc16 line per neighbor (coords + z)
    uint2 cjN0 = cj0, cjN1 = cj1;
    float zN0 = 0.f, zN1 = 0.f, mN0 = 0.f, mN1 = 0.f;
    if (kn + 1 < KK) {
      int ja = sm.g.jm[r0][kn + 1], jb = sm.g.jm[r1][kn + 1];
      int jja = max(ja, 0), jjb = max(jb, 0);
      cjN0 = *(const uint2*)(zc16 + (size_t)jja * 32);
      cjN1 = *(const uint2*)(zc16 + (size_t)jjb * 32);
      if (cc0 == 0) {
        if (ja >= 0) zN0 = b2f(zc16[(size_t)ja * 32 + 4 + kn + 1]);
        if (jb >= 0) zN1 = b2f(zc16[(size_t)jb * 32 + 4 + kn + 1]);
      }
      mN0 = (ja >= 0) ? 1.f : 0.f; mN1 = (jb >= 0) ? 1.f : 0.f;
    }
    // (4) issue v(kn+2) -> R; stays outstanding across the barrier
    R0 = make_uint4(0u,0u,0u,0u); R1 = R0;
    if (kn + 2 < KK) {
      int j0 = sm.g.jm[r0][kn + 2], j1 = sm.g.jm[r1][kn + 2];
      if (j0 >= 0) R0 = *(const uint4*)(v + (size_t)j0 * PC + ch0);
      if (j1 >= 0) R1 = *(const uint4*)(v + (size_t)j1 * PC + ch0);
    }
    // (5) q-compute for kn (pos-MLP 8ch; z rides on lane cc0==0)
    {
      float wqv[8] = {wqA.x, wqA.y, wqA.z, wqA.w, wqB.x, wqB.y, wqB.z, wqB.w};
      float rx0 = (float)((int)(cj0.x & 0xffffu) - cx0);
      float ry0 = (float)((int)(cj0.x >> 16) - cy0);
      float rz0 = (float)((int)(cj0.y & 0xffffu) - cz0);
      float rx1 = (float)((int)(cj1.x & 0xffffu) - cx1);
      float ry1 = (float)((int)(cj1.x >> 16) - cy1);
      float rz1 = (float)((int)(cj1.y & 0xffffu) - cz1);
      float t0 = 0.f, t1 = 0.f;
      #pragma unroll
      for (int c = 0; c < 8; ++c) {
        float p0 = fmaxf(rx0 * wpr0[c] + ry0 * wpr1[c] + rz0 * wpr2[c] + bpr[c], 0.f);
        float p1 = fmaxf(rx1 * wpr0[c] + ry1 * wpr1[c] + rz1 * wpr2[c] + bpr[c], 0.f);
        t0 += p0 * wqv[c];
        t1 += p1 * wqv[c];
      }
      qp0 += mc0 * t0 + zc0;
      qp1 += mc1 * t1 + zc1;
    }
    // (6) A fragments + MFMA on As[cur]
    #pragma unroll
    for (int s2 = 0; s2 < 2; ++s2) {
      v8s af[4];
      const int cc = s2 * 4 + (lane >> 4);
      #pragma unroll
      for (int mt = 0; mt < 4; ++mt) {
        const int r = mt * 16 + (lane & 15);
        const int sc = cc ^ (r & 7);
        af[mt] = *(const v8s*)(&sm.g.As[cur][r * 64 + sc * 8]);
      }
      #pragma unroll
      for (int mt = 0; mt < 4; ++mt)
        #pragma unroll
        for (int nt = 0; nt < 4; ++nt)
          acc[mt][nt] = __builtin_amdgcn_mfma_f32_16x16x32_bf16(
              af[mt], (s2 ? bf1[nt] : bf0[nt]), acc[mt][nt], 0, 0, 0);
    }
    __syncthreads();
    cur = nxb; nxb = (nxb == 2) ? 0 : nxb + 1;
    cj0 = cjN0; cj1 = cjN1;
    zc0 = zN0; zc1 = zN1;
    mc0 = mN0; mc1 = mN1;
  }

  // ---- q reduce (8 lanes per row; z rides on lane cc0==0) + softmax -> attnL
  qp0 += __shfl_xor(qp0, 1); qp0 += __shfl_xor(qp0, 2); qp0 += __shfl_xor(qp0, 4);
  qp1 += __shfl_xor(qp1, 1); qp1 += __shfl_xor(qp1, 2); qp1 += __shfl_xor(qp1, 4);
  if (cc0 == 0) {
    float qs[2] = {qp0, qp1};
    int rr[2] = {r0, r1};
    #pragma unroll
    for (int h = 0; h < 2; ++h) {
      float q = fmaxf(qs[h] + bq0, 0.f);
      float lg[4], mx = -1e30f;
      #pragma unroll
      for (int m = 0; m < 4; ++m) { lg[m] = q * pj[m]; mx = fmaxf(mx, lg[m]); }
      float s = 0.f;
      #pragma unroll
      for (int m = 0; m < 4; ++m) { lg[m] = __expf(lg[m] - mx); s += lg[m]; }
      float inv = 1.f / s;
      #pragma unroll
      for (int m = 0; m < 4; ++m) attnL[rr[h]][m] = lg[m] * inv;
    }
  }

  // ---- epilogue: per-lane m-sum + MFMA residual
  for (int i2 = tid; i2 < 2048; i2 += 256) {
    int r = i2 >> 5, c = i2 & 31;
    int n = base + r;
    sm.e.xfb[r][c] = (n < N) ? f2b(xf[(size_t)n * INC + c]) : (ushort)0;
  }
  __syncthreads();

  const int ln = lane & 15, grp = lane >> 4;
  const int d = (w << 4) + ln;
  v8s wdf = *(const v8s*)(Wdp + (size_t)d * 32 + grp * 8);
  f32x4 res[4];
  #pragma unroll
  for (int mt = 0; mt < 4; ++mt) {
    v8s af = *(const v8s*)(&sm.e.xfb[mt * 16 + ln][grp * 8]);
    f32x4 zz = {0.f, 0.f, 0.f, 0.f};
    res[mt] = __builtin_amdgcn_mfma_f32_16x16x32_bf16(af, wdf, zz, 0, 0, 0);
  }
  float bcv[4];
  #pragma unroll
  for (int nt = 0; nt < 4; ++nt) bcv[nt] = bcode[nt * PC + d];
  const float bdv = bd[d];
  #pragma unroll
  for (int mt = 0; mt < 4; ++mt) {
    #pragma unroll
    for (int i = 0; i < 4; ++i) {
      int row = mt * 16 + grp * 4 + i;
      int n = base + row;
      if (n < N) {
        float4 a4 = *(const float4*)(&attnL[row][0]);
        float val = res[mt][i] + bdv;
        val += a4.x * fmaxf(acc[mt][0][i] + bcv[0], 0.f);
        val += a4.y * fmaxf(acc[mt][1][i] + bcv[1], 0.f);
        val += a4.z * fmaxf(acc[mt][2][i] + bcv[2], 0.f);
        val += a4.w * fmaxf(acc[mt][3][i] + bcv[3], 0.f);
        out[(size_t)n * PC + d] = fmaxf(val, 0.f);
      }
    }
  }
}

extern "C" void kernel_launch(void* const* d_in, const int* in_sizes, int n_in,
                              void* d_out, int out_size, void* d_ws, size_t ws_size,
                              hipStream_t stream)
{
  const float* xf     = (const float*)d_in[0];
  const int* nbr_idx  = (const int*)d_in[1];
  const int* nbr_mask = (const int*)d_in[2];
  const int* coords   = (const int*)d_in[3];
  const float* Wt     = (const float*)d_in[4];
  const float* bt     = (const float*)d_in[5];
  const float* Wd     = (const float*)d_in[6];
  const float* bd     = (const float*)d_in[7];
  const float* Wpos   = (const float*)d_in[8];
  const float* bpos   = (const float*)d_in[9];
  const float* Wq     = (const float*)d_in[10];
  const float* bq     = (const float*)d_in[11];
  const float* proj   = (const float*)d_in[12];
  const float* Wv     = (const float*)d_in[13];
  const float* bv     = (const float*)d_in[14];
  const float* Wcode  = (const float*)d_in[15];
  const float* bcode  = (const float*)d_in[16];
  float* out = (float*)d_out;

  int N = in_sizes[0] / INC;

  char* ws = (char*)d_ws;
  size_t off = 0;
  auto alloc = [&](size_t bytes) {
    off = (off + 255) & ~(size_t)255;
    void* p = ws + off;
    off += bytes;
    return p;
  };
  ushort* v_ws  = (ushort*)alloc((size_t)N * PC * 2);
  ushort* zc_ws = (ushort*)alloc((size_t)N * 32 * 2);
  ushort* B_ws  = (ushort*)alloc((size_t)54 * 4 * 256 * 8 * 2);
  ushort* D_ws  = (ushort*)alloc((size_t)2048 * 2);
  (void)ws_size;

  hipLaunchKernelGGL(k_prepBD, dim3(1736), dim3(256), 0, stream,
                     Wcode, Wd, B_ws, D_ws);
  hipLaunchKernelGGL(k_prep, dim3((N + 15) / 16), dim3(256), 0, stream,
                     xf, Wt, bt, Wv, bv, Wq, coords, v_ws, zc_ws, N);
  hipLaunchKernelGGL(k_code, dim3((N + 63) / 64), dim3(256), 0, stream,
                     v_ws, nbr_idx, nbr_mask, B_ws, zc_ws,
                     Wpos, bpos, Wq, bq, proj, xf, D_ws, bd, bcode, out, N);
}

// Round 14
// 333.089 us; speedup vs baseline: 1.2122x; 1.2122x over previous
//
#include <hip/hip_runtime.h>

#define KK 27
#define INC 32
#define PC 64

typedef __attribute__((ext_vector_type(8))) short v8s;
typedef __attribute__((ext_vector_type(4))) float f32x4;

static __device__ __forceinline__ float b2f(ushort u) {
  union { float f; unsigned int i; } x; x.i = ((unsigned int)u) << 16; return x.f;
}
static __device__ __forceinline__ ushort f2b(float f) {
  union { float f; unsigned int i; } x; x.f = f;
  unsigned int u = x.i;
  unsigned int r = (u + 0x7FFFu + ((u >> 16) & 1u)) >> 16;
  return (ushort)r;
}

// ---------------- Kernel 1: x=relu(xf@Wt+bt) (LDS only), v=relu(x@Wv+bv) [bf16],
// zc16[n] = one 64B line: [cx,cy,cz,pad (ushort)] + z[n][k]=dot(x,Wq_k) bf16 x27
__global__ __launch_bounds__(256) void k_prep(
    const float* __restrict__ xf, const float* __restrict__ Wt, const float* __restrict__ bt,
    const float* __restrict__ Wv, const float* __restrict__ bv,
    const float* __restrict__ Wq, const int* __restrict__ coords,
    ushort* __restrict__ v, ushort* __restrict__ zc16, int N)
{
  int tid = threadIdx.x, lane = tid & 63, w = tid >> 6;
  int vbase = blockIdx.x * 16;
  __shared__ float xin[16][32];
  __shared__ float xs[16][64];
  if (tid < 128) {
    int r = tid >> 3, c4 = tid & 7;
    int n = vbase + r;
    float4 d = make_float4(0.f, 0.f, 0.f, 0.f);
    if (n < N) d = *(const float4*)(xf + (size_t)n * INC + c4 * 4);
    *(float4*)(&xin[r][c4 * 4]) = d;
  }
  __syncthreads();
  float a0 = bt[lane], a1 = a0, a2 = a0, a3 = a0;
  #pragma unroll
  for (int i = 0; i < INC; ++i) {
    float wt = Wt[i * PC + lane];
    a0 += xin[w * 4 + 0][i] * wt; a1 += xin[w * 4 + 1][i] * wt;
    a2 += xin[w * 4 + 2][i] * wt; a3 += xin[w * 4 + 3][i] * wt;
  }
  a0 = fmaxf(a0, 0.f); a1 = fmaxf(a1, 0.f); a2 = fmaxf(a2, 0.f); a3 = fmaxf(a3, 0.f);
  xs[w * 4 + 0][lane] = a0; xs[w * 4 + 1][lane] = a1;
  xs[w * 4 + 2][lane] = a2; xs[w * 4 + 3][lane] = a3;
  __syncthreads();
  // v = relu(x@Wv+bv)
  float v0 = bv[lane], v1 = v0, v2 = v0, v3 = v0;
  #pragma unroll
  for (int i = 0; i < PC; ++i) {
    float wv = Wv[i * PC + lane];
    v0 += xs[w * 4 + 0][i] * wv; v1 += xs[w * 4 + 1][i] * wv;
    v2 += xs[w * 4 + 2][i] * wv; v3 += xs[w * 4 + 3][i] * wv;
  }
  {
    int n0 = vbase + w * 4;
    if (n0 + 0 < N) v[(size_t)(n0 + 0) * PC + lane] = f2b(fmaxf(v0, 0.f));
    if (n0 + 1 < N) v[(size_t)(n0 + 1) * PC + lane] = f2b(fmaxf(v1, 0.f));
    if (n0 + 2 < N) v[(size_t)(n0 + 2) * PC + lane] = f2b(fmaxf(v2, 0.f));
    if (n0 + 3 < N) v[(size_t)(n0 + 3) * PC + lane] = f2b(fmaxf(v3, 0.f));
  }
  // z-tail: voxel g = tid>>4, lane-in-group l = tid&15; plain dot64 per (g,k)
  {
    int g = tid >> 4, l = tid & 15;
    int nz = vbase + g;
    if (nz < N) {
      ushort* row = zc16 + (size_t)nz * 32;
      #pragma unroll
      for (int h = 0; h < 2; ++h) {
        int k = l + h * 16;
        if (k < KK) {
          float zv = 0.f;
          #pragma unroll
          for (int c4 = 0; c4 < 16; ++c4) {
            float4 xv4 = *(const float4*)(&xs[g][c4 * 4]);
            float4 wq4 = *(const float4*)(Wq + k * PC + c4 * 4);
            zv += xv4.x * wq4.x + xv4.y * wq4.y + xv4.z * wq4.z + xv4.w * wq4.w;
          }
          row[4 + k] = f2b(zv);
        }
      }
      if (l == 0) {
        row[0] = (ushort)coords[nz * 3 + 0];
        row[1] = (ushort)coords[nz * 3 + 1];
        row[2] = (ushort)coords[nz * 3 + 2];
        row[3] = 0;
      }
    }
  }
}

// ---------------- Kernel 2: repack W_code -> Bp, and Wd -> Wdp (fused)
__global__ __launch_bounds__(256) void k_prepBD(
    const float* __restrict__ Wcode, const float* __restrict__ Wd,
    ushort* __restrict__ Bp, ushort* __restrict__ Wdp)
{
  int bid = blockIdx.x;
  if (bid < 1728) {
    int i = bid * 256 + threadIdx.x;   // 54*4*256*8 = 442368
    int j = i & 7;
    int col = (i >> 3) & 255;
    int kg = (i >> 11) & 3;
    int s = i >> 13;
    int k = s * 32 + kg * 8 + j;
    int m = col >> 6, d = col & 63;
    int knbr = k >> 6, c = k & 63;
    Bp[i] = f2b(Wcode[(((m * KK + knbr) * 64) + c) * 64 + d]);
  } else {
    int i = (bid - 1728) * 256 + threadIdx.x;   // 2048
    int col = i >> 5, k = i & 31;
    Wdp[i] = f2b(Wd[k * PC + col]);
  }
}

// ---------------- Kernel 3: PARALLEL-k attention. Wave = 2 voxels x 32 lanes;
// lane l = neighbor k. All 27 gathers per voxel issue concurrently (one 64B
// zc16 line each: coords + precomputed z). 64-ch pos-dot from L1-hot Wpos/Wq.
__global__ __launch_bounds__(256) void k_attn2(
    const int* __restrict__ nbr_idx, const int* __restrict__ nbr_mask,
    const ushort* __restrict__ zc16,
    const float* __restrict__ Wpos, const float* __restrict__ bpos,
    const float* __restrict__ Wq, const float* __restrict__ bq,
    const float* __restrict__ proj, float* __restrict__ attn, int N)
{
  int tid = threadIdx.x;
  int wv = tid >> 6, lane = tid & 63;
  int half = lane >> 5, l = lane & 31;
  int n = blockIdx.x * 8 + wv * 2 + half;
  bool vok = (n < N);
  int j = -1;
  if (vok && l < KK) {
    if (nbr_mask[(size_t)n * KK + l]) j = nbr_idx[(size_t)n * KK + l];
  }
  int cx = 0, cy = 0, cz = 0;
  if (vok) {
    uint2 cd = *(const uint2*)(zc16 + (size_t)n * 32);
    cx = (int)(cd.x & 0xffffu); cy = (int)(cd.x >> 16); cz = (int)(cd.y & 0xffffu);
  }
  float qc = 0.f;
  if (j >= 0) {
    uint2 cj = *(const uint2*)(zc16 + (size_t)j * 32);
    float z = b2f(zc16[(size_t)j * 32 + 4 + l]);
    float rx = (float)((int)(cj.x & 0xffffu) - cx);
    float ry = (float)((int)(cj.x >> 16) - cy);
    float rz = (float)((int)(cj.y & 0xffffu) - cz);
    float t = 0.f;
    #pragma unroll
    for (int c4 = 0; c4 < 16; ++c4) {
      float4 w0 = *(const float4*)(Wpos + c4 * 4);
      float4 w1 = *(const float4*)(Wpos + 64 + c4 * 4);
      float4 w2 = *(const float4*)(Wpos + 128 + c4 * 4);
      float4 bp = *(const float4*)(bpos + c4 * 4);
      float4 wq = *(const float4*)(Wq + (size_t)l * PC + c4 * 4);
      t += fmaxf(rx * w0.x + ry * w1.x + rz * w2.x + bp.x, 0.f) * wq.x;
      t += fmaxf(rx * w0.y + ry * w1.y + rz * w2.y + bp.y, 0.f) * wq.y;
      t += fmaxf(rx * w0.z + ry * w1.z + rz * w2.z + bp.z, 0.f) * wq.z;
      t += fmaxf(rx * w0.w + ry * w1.w + rz * w2.w + bp.w, 0.f) * wq.w;
    }
    qc = z + t;
  }
  // reduce 32 lanes within each half (xor offsets stay inside the half)
  qc += __shfl_xor(qc, 1); qc += __shfl_xor(qc, 2); qc += __shfl_xor(qc, 4);
  qc += __shfl_xor(qc, 8); qc += __shfl_xor(qc, 16);
  if (vok && l == 0) {
    float q = fmaxf(qc + bq[0], 0.f);
    float lg[4], mx = -1e30f;
    #pragma unroll
    for (int m = 0; m < 4; ++m) { lg[m] = q * proj[m] * 0.1f; mx = fmaxf(mx, lg[m]); }
    float s = 0.f;
    #pragma unroll
    for (int m = 0; m < 4; ++m) { lg[m] = __expf(lg[m] - mx); s += lg[m]; }
    float inv = 1.f / s;
    #pragma unroll
    for (int m = 0; m < 4; ++m) attn[(size_t)n * 4 + m] = lg[m] * inv;
  }
}

// ---------------- Kernel 4: gathered GEMM [64x1728]x[1728x256] — R9 core verbatim.
// Wave w owns cols {m*64 + w*16 + ln} -> per-lane m-sum, no cross-wave epilogue.
// 3-buffer LDS ring, early commit, B-before-gather. Residual via 4 MFMAs.
__global__ __launch_bounds__(256) void k_code(
    const ushort* __restrict__ v, const int* __restrict__ nbr_idx, const int* __restrict__ nbr_mask,
    const ushort* __restrict__ Bp, const float* __restrict__ attn,
    const float* __restrict__ xf, const ushort* __restrict__ Wdp, const float* __restrict__ bd,
    const float* __restrict__ bcode, float* __restrict__ out, int N)
{
  const int tid = threadIdx.x;
  const int lane = tid & 63, w = tid >> 6;
  const int base = blockIdx.x * 64;

  __shared__ __align__(16) union SM {
    struct { ushort As[3][4096]; int jm[64][KK]; } g;   // GEMM phase (31.5 KB)
    struct { ushort xfb[64][40]; } e;                   // epilogue (5.1 KB)
  } sm;

  for (int i = tid; i < 64 * KK; i += 256) {
    int r = i / KK, k = i % KK;
    int n = base + r;
    int val = -1;
    if (n < N && nbr_mask[(size_t)n * KK + k]) val = nbr_idx[(size_t)n * KK + k];
    sm.g.jm[r][k] = val;
  }

  const int r0 = tid >> 3, cc0 = tid & 7;
  const int r1 = r0 + 32,  cc1 = cc0;
  const int sc0 = cc0 ^ (r0 & 7), sc1 = cc1 ^ (r1 & 7);

  __syncthreads();  // jm ready

  // prologue: gather(0) -> As[0]; gather(1) -> regs R
  uint4 R0 = make_uint4(0u,0u,0u,0u), R1 = R0;
  {
    int j0 = sm.g.jm[r0][0], j1 = sm.g.jm[r1][0];
    uint4 p0 = make_uint4(0u, 0u, 0u, 0u), p1 = p0;
    if (j0 >= 0) p0 = *(const uint4*)(v + (size_t)j0 * PC + cc0 * 8);
    if (j1 >= 0) p1 = *(const uint4*)(v + (size_t)j1 * PC + cc1 * 8);
    int jc = sm.g.jm[r0][1], jd = sm.g.jm[r1][1];
    if (jc >= 0) R0 = *(const uint4*)(v + (size_t)jc * PC + cc0 * 8);
    if (jd >= 0) R1 = *(const uint4*)(v + (size_t)jd * PC + cc1 * 8);
    *(uint4*)(&sm.g.As[0][r0 * 64 + sc0 * 8]) = p0;
    *(uint4*)(&sm.g.As[0][r1 * 64 + sc1 * 8]) = p1;
  }
  __syncthreads();

  f32x4 acc[4][4] = {};
  // col = nt*64 + w*16 + (lane&15)  -> nt stride = 512 ushorts
  const ushort* bbase = Bp + (size_t)(lane >> 4) * 2048 + (size_t)((w << 4) + (lane & 15)) * 8;

  int cur = 0, nx = 1;
  for (int kn = 0; kn < KK; ++kn) {
    // (1) B fragments — issued FIRST (short-latency; MFMA's vmcnt stops here)
    v8s bf0[4], bf1[4];
    {
      const ushort* bb0 = bbase + (size_t)(8 * kn) * 2048;
      const ushort* bb1 = bb0 + 4 * 2048;
      #pragma unroll
      for (int nt = 0; nt < 4; ++nt) {
        bf0[nt] = *(const v8s*)(bb0 + nt * 512);
        bf1[nt] = *(const v8s*)(bb1 + nt * 512);
      }
    }
    // (2) EARLY COMMIT: gather(kn+1), in flight since last iteration -> As[nx]
    if (kn + 1 < KK) {
      *(uint4*)(&sm.g.As[nx][r0 * 64 + sc0 * 8]) = R0;
      *(uint4*)(&sm.g.As[nx][r1 * 64 + sc1 * 8]) = R1;
    }
    // (3) issue gather(kn+2) -> R; stays outstanding across the barrier
    R0 = make_uint4(0u,0u,0u,0u); R1 = R0;
    if (kn + 2 < KK) {
      int j0 = sm.g.jm[r0][kn + 2], j1 = sm.g.jm[r1][kn + 2];
      if (j0 >= 0) R0 = *(const uint4*)(v + (size_t)j0 * PC + cc0 * 8);
      if (j1 >= 0) R1 = *(const uint4*)(v + (size_t)j1 * PC + cc1 * 8);
    }
    // (4) A fragments + MFMA on As[cur]
    #pragma unroll
    for (int s2 = 0; s2 < 2; ++s2) {
      v8s af[4];
      const int cc = s2 * 4 + (lane >> 4);
      #pragma unroll
      for (int mt = 0; mt < 4; ++mt) {
        const int r = mt * 16 + (lane & 15);
        const int sc = cc ^ (r & 7);
        af[mt] = *(const v8s*)(&sm.g.As[cur][r * 64 + sc * 8]);
      }
      #pragma unroll
      for (int mt = 0; mt < 4; ++mt)
        #pragma unroll
        for (int nt = 0; nt < 4; ++nt)
          acc[mt][nt] = __builtin_amdgcn_mfma_f32_16x16x32_bf16(
              af[mt], (s2 ? bf1[nt] : bf0[nt]), acc[mt][nt], 0, 0, 0);
    }
    __syncthreads();
    cur = nx; nx = (nx == 2) ? 0 : nx + 1;
  }

  // ---- epilogue (no cross-wave traffic): per-lane m-sum + MFMA residual
  for (int i2 = tid; i2 < 2048; i2 += 256) {
    int r = i2 >> 5, c = i2 & 31;
    int n = base + r;
    sm.e.xfb[r][c] = (n < N) ? f2b(xf[(size_t)n * INC + c]) : (ushort)0;
  }
  __syncthreads();

  const int ln = lane & 15, grp = lane >> 4;
  const int d = (w << 4) + ln;
  // residual = xf @ Wd via 4 MFMAs (K=32)
  v8s wdf = *(const v8s*)(Wdp + (size_t)d * 32 + grp * 8);
  f32x4 res[4];
  #pragma unroll
  for (int mt = 0; mt < 4; ++mt) {
    v8s af = *(const v8s*)(&sm.e.xfb[mt * 16 + ln][grp * 8]);
    f32x4 z = {0.f, 0.f, 0.f, 0.f};
    res[mt] = __builtin_amdgcn_mfma_f32_16x16x32_bf16(af, wdf, z, 0, 0, 0);
  }
  float bcv[4];
  #pragma unroll
  for (int nt = 0; nt < 4; ++nt) bcv[nt] = bcode[nt * PC + d];
  const float bdv = bd[d];
  #pragma unroll
  for (int mt = 0; mt < 4; ++mt) {
    #pragma unroll
    for (int i = 0; i < 4; ++i) {
      int row = mt * 16 + grp * 4 + i;
      int n = base + row;
      if (n < N) {
        float4 a4 = *(const float4*)(attn + (size_t)n * 4);
        float val = res[mt][i] + bdv;
        val += a4.x * fmaxf(acc[mt][0][i] + bcv[0], 0.f);
        val += a4.y * fmaxf(acc[mt][1][i] + bcv[1], 0.f);
        val += a4.z * fmaxf(acc[mt][2][i] + bcv[2], 0.f);
        val += a4.w * fmaxf(acc[mt][3][i] + bcv[3], 0.f);
        out[(size_t)n * PC + d] = fmaxf(val, 0.f);
      }
    }
  }
}

extern "C" void kernel_launch(void* const* d_in, const int* in_sizes, int n_in,
                              void* d_out, int out_size, void* d_ws, size_t ws_size,
                              hipStream_t stream)
{
  const float* xf     = (const float*)d_in[0];
  const int* nbr_idx  = (const int*)d_in[1];
  const int* nbr_mask = (const int*)d_in[2];
  const int* coords   = (const int*)d_in[3];
  const float* Wt     = (const float*)d_in[4];
  const float* bt     = (const float*)d_in[5];
  const float* Wd     = (const float*)d_in[6];
  const float* bd     = (const float*)d_in[7];
  const float* Wpos   = (const float*)d_in[8];
  const float* bpos   = (const float*)d_in[9];
  const float* Wq     = (const float*)d_in[10];
  const float* bq     = (const float*)d_in[11];
  const float* proj   = (const float*)d_in[12];
  const float* Wv     = (const float*)d_in[13];
  const float* bv     = (const float*)d_in[14];
  const float* Wcode  = (const float*)d_in[15];
  const float* bcode  = (const float*)d_in[16];
  float* out = (float*)d_out;

  int N = in_sizes[0] / INC;

  char* ws = (char*)d_ws;
  size_t off = 0;
  auto alloc = [&](size_t bytes) {
    off = (off + 255) & ~(size_t)255;
    void* p = ws + off;
    off += bytes;
    return p;
  };
  ushort* v_ws  = (ushort*)alloc((size_t)N * PC * 2);
  ushort* zc_ws = (ushort*)alloc((size_t)N * 32 * 2);
  float*  a_ws  = (float*)alloc((size_t)N * 4 * 4);
  ushort* B_ws  = (ushort*)alloc((size_t)54 * 4 * 256 * 8 * 2);
  ushort* D_ws  = (ushort*)alloc((size_t)2048 * 2);
  (void)ws_size;

  hipLaunchKernelGGL(k_prepBD, dim3(1736), dim3(256), 0, stream,
                     Wcode, Wd, B_ws, D_ws);
  hipLaunchKernelGGL(k_prep, dim3((N + 15) / 16), dim3(256), 0, stream,
                     xf, Wt, bt, Wv, bv, Wq, coords, v_ws, zc_ws, N);
  hipLaunchKernelGGL(k_attn2, dim3((N + 7) / 8), dim3(256), 0, stream,
                     nbr_idx, nbr_mask, zc_ws, Wpos, bpos, Wq, bq, proj, a_ws, N);
  hipLaunchKernelGGL(k_code, dim3((N + 63) / 64), dim3(256), 0, stream,
                     v_ws, nbr_idx, nbr_mask, B_ws, a_ws, xf, D_ws, bd, bcode, out, N);
}

// Round 15
// 299.682 us; speedup vs baseline: 1.3474x; 1.1115x over previous
//
#include <hip/hip_runtime.h>

#define KK 27
#define INC 32
#define PC 64

typedef __attribute__((ext_vector_type(8))) short v8s;
typedef __attribute__((ext_vector_type(4))) float f32x4;

static __device__ __forceinline__ float b2f(ushort u) {
  union { float f; unsigned int i; } x; x.i = ((unsigned int)u) << 16; return x.f;
}
static __device__ __forceinline__ ushort f2b(float f) {
  union { float f; unsigned int i; } x; x.f = f;
  unsigned int u = x.i;
  unsigned int r = (u + 0x7FFFu + ((u >> 16) & 1u)) >> 16;
  return (ushort)r;
}

// ---------------- Kernel 1: x=relu(xf@Wt+bt) (LDS only), v=relu(x@Wv+bv) [bf16],
// zc16[n] = one 64B line: [cx,cy,cz,pad (ushort)] + z[n][k]=dot(x,Wq_k) bf16 x27
// R15: xs padded to 68 (kills 4-way z-tail bank conflict); Wq staged in LDS
__global__ __launch_bounds__(256) void k_prep(
    const float* __restrict__ xf, const float* __restrict__ Wt, const float* __restrict__ bt,
    const float* __restrict__ Wv, const float* __restrict__ bv,
    const float* __restrict__ Wq, const int* __restrict__ coords,
    ushort* __restrict__ v, ushort* __restrict__ zc16, int N)
{
  int tid = threadIdx.x, lane = tid & 63, w = tid >> 6;
  int vbase = blockIdx.x * 16;
  __shared__ float xin[16][32];
  __shared__ float xs[16][68];    // pad 68: group stride -> banks {0,4,8,12}
  __shared__ float wqs[27][68];   // Wq staged once; row stride 68 -> 2-way max
  if (tid < 128) {
    int r = tid >> 3, c4 = tid & 7;
    int n = vbase + r;
    float4 d = make_float4(0.f, 0.f, 0.f, 0.f);
    if (n < N) d = *(const float4*)(xf + (size_t)n * INC + c4 * 4);
    *(float4*)(&xin[r][c4 * 4]) = d;
  }
  for (int i = tid; i < KK * PC; i += 256)
    wqs[i >> 6][i & 63] = Wq[i];
  __syncthreads();
  float a0 = bt[lane], a1 = a0, a2 = a0, a3 = a0;
  #pragma unroll
  for (int i = 0; i < INC; ++i) {
    float wt = Wt[i * PC + lane];
    a0 += xin[w * 4 + 0][i] * wt; a1 += xin[w * 4 + 1][i] * wt;
    a2 += xin[w * 4 + 2][i] * wt; a3 += xin[w * 4 + 3][i] * wt;
  }
  a0 = fmaxf(a0, 0.f); a1 = fmaxf(a1, 0.f); a2 = fmaxf(a2, 0.f); a3 = fmaxf(a3, 0.f);
  xs[w * 4 + 0][lane] = a0; xs[w * 4 + 1][lane] = a1;
  xs[w * 4 + 2][lane] = a2; xs[w * 4 + 3][lane] = a3;
  __syncthreads();
  // v = relu(x@Wv+bv)
  float v0 = bv[lane], v1 = v0, v2 = v0, v3 = v0;
  #pragma unroll
  for (int i = 0; i < PC; ++i) {
    float wv = Wv[i * PC + lane];
    v0 += xs[w * 4 + 0][i] * wv; v1 += xs[w * 4 + 1][i] * wv;
    v2 += xs[w * 4 + 2][i] * wv; v3 += xs[w * 4 + 3][i] * wv;
  }
  {
    int n0 = vbase + w * 4;
    if (n0 + 0 < N) v[(size_t)(n0 + 0) * PC + lane] = f2b(fmaxf(v0, 0.f));
    if (n0 + 1 < N) v[(size_t)(n0 + 1) * PC + lane] = f2b(fmaxf(v1, 0.f));
    if (n0 + 2 < N) v[(size_t)(n0 + 2) * PC + lane] = f2b(fmaxf(v2, 0.f));
    if (n0 + 3 < N) v[(size_t)(n0 + 3) * PC + lane] = f2b(fmaxf(v3, 0.f));
  }
  // z-tail: voxel g = tid>>4, lane l = tid&15 handles k=l and k=l+16; LDS-only
  {
    int g = tid >> 4, l = tid & 15;
    int nz = vbase + g;
    if (nz < N) {
      ushort* row = zc16 + (size_t)nz * 32;
      #pragma unroll
      for (int h = 0; h < 2; ++h) {
        int k = l + h * 16;
        if (k < KK) {
          float zv = 0.f;
          #pragma unroll 8
          for (int c4 = 0; c4 < 16; ++c4) {
            float4 xv4 = *(const float4*)(&xs[g][c4 * 4]);
            float4 wq4 = *(const float4*)(&wqs[k][c4 * 4]);
            zv += xv4.x * wq4.x + xv4.y * wq4.y + xv4.z * wq4.z + xv4.w * wq4.w;
          }
          row[4 + k] = f2b(zv);
        }
      }
      if (l == 0) {
        row[0] = (ushort)coords[nz * 3 + 0];
        row[1] = (ushort)coords[nz * 3 + 1];
        row[2] = (ushort)coords[nz * 3 + 2];
        row[3] = 0;
      }
    }
  }
}

// ---------------- Kernel 2: repack W_code -> Bp, and Wd -> Wdp (fused)
__global__ __launch_bounds__(256) void k_prepBD(
    const float* __restrict__ Wcode, const float* __restrict__ Wd,
    ushort* __restrict__ Bp, ushort* __restrict__ Wdp)
{
  int bid = blockIdx.x;
  if (bid < 1728) {
    int i = bid * 256 + threadIdx.x;   // 54*4*256*8 = 442368
    int j = i & 7;
    int col = (i >> 3) & 255;
    int kg = (i >> 11) & 3;
    int s = i >> 13;
    int k = s * 32 + kg * 8 + j;
    int m = col >> 6, d = col & 63;
    int knbr = k >> 6, c = k & 63;
    Bp[i] = f2b(Wcode[(((m * KK + knbr) * 64) + c) * 64 + d]);
  } else {
    int i = (bid - 1728) * 256 + threadIdx.x;   // 2048
    int col = i >> 5, k = i & 31;
    Wdp[i] = f2b(Wd[k * PC + col]);
  }
}

// ---------------- Kernel 3: PARALLEL-k attention. Wave = 2 voxels x 32 lanes;
// lane l = neighbor k. All 27 gathers per voxel issue concurrently (one 64B
// zc16 line each: coords + precomputed z). 64-ch pos-dot from L1-hot Wpos/Wq.
__global__ __launch_bounds__(256) void k_attn2(
    const int* __restrict__ nbr_idx, const int* __restrict__ nbr_mask,
    const ushort* __restrict__ zc16,
    const float* __restrict__ Wpos, const float* __restrict__ bpos,
    const float* __restrict__ Wq, const float* __restrict__ bq,
    const float* __restrict__ proj, float* __restrict__ attn, int N)
{
  int tid = threadIdx.x;
  int wv = tid >> 6, lane = tid & 63;
  int half = lane >> 5, l = lane & 31;
  int n = blockIdx.x * 8 + wv * 2 + half;
  bool vok = (n < N);
  int j = -1;
  if (vok && l < KK) {
    if (nbr_mask[(size_t)n * KK + l]) j = nbr_idx[(size_t)n * KK + l];
  }
  int cx = 0, cy = 0, cz = 0;
  if (vok) {
    uint2 cd = *(const uint2*)(zc16 + (size_t)n * 32);
    cx = (int)(cd.x & 0xffffu); cy = (int)(cd.x >> 16); cz = (int)(cd.y & 0xffffu);
  }
  float qc = 0.f;
  if (j >= 0) {
    uint2 cj = *(const uint2*)(zc16 + (size_t)j * 32);
    float z = b2f(zc16[(size_t)j * 32 + 4 + l]);
    float rx = (float)((int)(cj.x & 0xffffu) - cx);
    float ry = (float)((int)(cj.x >> 16) - cy);
    float rz = (float)((int)(cj.y & 0xffffu) - cz);
    float t = 0.f;
    #pragma unroll
    for (int c4 = 0; c4 < 16; ++c4) {
      float4 w0 = *(const float4*)(Wpos + c4 * 4);
      float4 w1 = *(const float4*)(Wpos + 64 + c4 * 4);
      float4 w2 = *(const float4*)(Wpos + 128 + c4 * 4);
      float4 bp = *(const float4*)(bpos + c4 * 4);
      float4 wq = *(const float4*)(Wq + (size_t)l * PC + c4 * 4);
      t += fmaxf(rx * w0.x + ry * w1.x + rz * w2.x + bp.x, 0.f) * wq.x;
      t += fmaxf(rx * w0.y + ry * w1.y + rz * w2.y + bp.y, 0.f) * wq.y;
      t += fmaxf(rx * w0.z + ry * w1.z + rz * w2.z + bp.z, 0.f) * wq.z;
      t += fmaxf(rx * w0.w + ry * w1.w + rz * w2.w + bp.w, 0.f) * wq.w;
    }
    qc = z + t;
  }
  // reduce 32 lanes within each half (xor offsets stay inside the half)
  qc += __shfl_xor(qc, 1); qc += __shfl_xor(qc, 2); qc += __shfl_xor(qc, 4);
  qc += __shfl_xor(qc, 8); qc += __shfl_xor(qc, 16);
  if (vok && l == 0) {
    float q = fmaxf(qc + bq[0], 0.f);
    float lg[4], mx = -1e30f;
    #pragma unroll
    for (int m = 0; m < 4; ++m) { lg[m] = q * proj[m] * 0.1f; mx = fmaxf(mx, lg[m]); }
    float s = 0.f;
    #pragma unroll
    for (int m = 0; m < 4; ++m) { lg[m] = __expf(lg[m] - mx); s += lg[m]; }
    float inv = 1.f / s;
    #pragma unroll
    for (int m = 0; m < 4; ++m) attn[(size_t)n * 4 + m] = lg[m] * inv;
  }
}

// ---------------- Kernel 4: gathered GEMM [64x1728]x[1728x256] — R9 core verbatim.
// Wave w owns cols {m*64 + w*16 + ln} -> per-lane m-sum, no cross-wave epilogue.
// 3-buffer LDS ring, early commit, B-before-gather. Residual via 4 MFMAs.
__global__ __launch_bounds__(256) void k_code(
    const ushort* __restrict__ v, const int* __restrict__ nbr_idx, const int* __restrict__ nbr_mask,
    const ushort* __restrict__ Bp, const float* __restrict__ attn,
    const float* __restrict__ xf, const ushort* __restrict__ Wdp, const float* __restrict__ bd,
    const float* __restrict__ bcode, float* __restrict__ out, int N)
{
  const int tid = threadIdx.x;
  const int lane = tid & 63, w = tid >> 6;
  const int base = blockIdx.x * 64;

  __shared__ __align__(16) union SM {
    struct { ushort As[3][4096]; int jm[64][KK]; } g;   // GEMM phase (31.5 KB)
    struct { ushort xfb[64][40]; } e;                   // epilogue (5.1 KB)
  } sm;

  for (int i = tid; i < 64 * KK; i += 256) {
    int r = i / KK, k = i % KK;
    int n = base + r;
    int val = -1;
    if (n < N && nbr_mask[(size_t)n * KK + k]) val = nbr_idx[(size_t)n * KK + k];
    sm.g.jm[r][k] = val;
  }

  const int r0 = tid >> 3, cc0 = tid & 7;
  const int r1 = r0 + 32,  cc1 = cc0;
  const int sc0 = cc0 ^ (r0 & 7), sc1 = cc1 ^ (r1 & 7);

  __syncthreads();  // jm ready

  // prologue: gather(0) -> As[0]; gather(1) -> regs R
  uint4 R0 = make_uint4(0u,0u,0u,0u), R1 = R0;
  {
    int j0 = sm.g.jm[r0][0], j1 = sm.g.jm[r1][0];
    uint4 p0 = make_uint4(0u, 0u, 0u, 0u), p1 = p0;
    if (j0 >= 0) p0 = *(const uint4*)(v + (size_t)j0 * PC + cc0 * 8);
    if (j1 >= 0) p1 = *(const uint4*)(v + (size_t)j1 * PC + cc1 * 8);
    int jc = sm.g.jm[r0][1], jd = sm.g.jm[r1][1];
    if (jc >= 0) R0 = *(const uint4*)(v + (size_t)jc * PC + cc0 * 8);
    if (jd >= 0) R1 = *(const uint4*)(v + (size_t)jd * PC + cc1 * 8);
    *(uint4*)(&sm.g.As[0][r0 * 64 + sc0 * 8]) = p0;
    *(uint4*)(&sm.g.As[0][r1 * 64 + sc1 * 8]) = p1;
  }
  __syncthreads();

  f32x4 acc[4][4] = {};
  // col = nt*64 + w*16 + (lane&15)  -> nt stride = 512 ushorts
  const ushort* bbase = Bp + (size_t)(lane >> 4) * 2048 + (size_t)((w << 4) + (lane & 15)) * 8;

  int cur = 0, nx = 1;
  for (int kn = 0; kn < KK; ++kn) {
    // (1) B fragments — issued FIRST (short-latency; MFMA's vmcnt stops here)
    v8s bf0[4], bf1[4];
    {
      const ushort* bb0 = bbase + (size_t)(8 * kn) * 2048;
      const ushort* bb1 = bb0 + 4 * 2048;
      #pragma unroll
      for (int nt = 0; nt < 4; ++nt) {
        bf0[nt] = *(const v8s*)(bb0 + nt * 512);
        bf1[nt] = *(const v8s*)(bb1 + nt * 512);
      }
    }
    // (2) EARLY COMMIT: gather(kn+1), in flight since last iteration -> As[nx]
    if (kn + 1 < KK) {
      *(uint4*)(&sm.g.As[nx][r0 * 64 + sc0 * 8]) = R0;
      *(uint4*)(&sm.g.As[nx][r1 * 64 + sc1 * 8]) = R1;
    }
    // (3) issue gather(kn+2) -> R; stays outstanding across the barrier
    R0 = make_uint4(0u,0u,0u,0u); R1 = R0;
    if (kn + 2 < KK) {
      int j0 = sm.g.jm[r0][kn + 2], j1 = sm.g.jm[r1][kn + 2];
      if (j0 >= 0) R0 = *(const uint4*)(v + (size_t)j0 * PC + cc0 * 8);
      if (j1 >= 0) R1 = *(const uint4*)(v + (size_t)j1 * PC + cc1 * 8);
    }
    // (4) A fragments + MFMA on As[cur]
    #pragma unroll
    for (int s2 = 0; s2 < 2; ++s2) {
      v8s af[4];
      const int cc = s2 * 4 + (lane >> 4);
      #pragma unroll
      for (int mt = 0; mt < 4; ++mt) {
        const int r = mt * 16 + (lane & 15);
        const int sc = cc ^ (r & 7);
        af[mt] = *(const v8s*)(&sm.g.As[cur][r * 64 + sc * 8]);
      }
      #pragma unroll
      for (int mt = 0; mt < 4; ++mt)
        #pragma unroll
        for (int nt = 0; nt < 4; ++nt)
          acc[mt][nt] = __builtin_amdgcn_mfma_f32_16x16x32_bf16(
              af[mt], (s2 ? bf1[nt] : bf0[nt]), acc[mt][nt], 0, 0, 0);
    }
    __syncthreads();
    cur = nx; nx = (nx == 2) ? 0 : nx + 1;
  }

  // ---- epilogue (no cross-wave traffic): per-lane m-sum + MFMA residual
  for (int i2 = tid; i2 < 2048; i2 += 256) {
    int r = i2 >> 5, c = i2 & 31;
    int n = base + r;
    sm.e.xfb[r][c] = (n < N) ? f2b(xf[(size_t)n * INC + c]) : (ushort)0;
  }
  __syncthreads();

  const int ln = lane & 15, grp = lane >> 4;
  const int d = (w << 4) + ln;
  // residual = xf @ Wd via 4 MFMAs (K=32)
  v8s wdf = *(const v8s*)(Wdp + (size_t)d * 32 + grp * 8);
  f32x4 res[4];
  #pragma unroll
  for (int mt = 0; mt < 4; ++mt) {
    v8s af = *(const v8s*)(&sm.e.xfb[mt * 16 + ln][grp * 8]);
    f32x4 z = {0.f, 0.f, 0.f, 0.f};
    res[mt] = __builtin_amdgcn_mfma_f32_16x16x32_bf16(af, wdf, z, 0, 0, 0);
  }
  float bcv[4];
  #pragma unroll
  for (int nt = 0; nt < 4; ++nt) bcv[nt] = bcode[nt * PC + d];
  const float bdv = bd[d];
  #pragma unroll
  for (int mt = 0; mt < 4; ++mt) {
    #pragma unroll
    for (int i = 0; i < 4; ++i) {
      int row = mt * 16 + grp * 4 + i;
      int n = base + row;
      if (n < N) {
        float4 a4 = *(const float4*)(attn + (size_t)n * 4);
        float val = res[mt][i] + bdv;
        val += a4.x * fmaxf(acc[mt][0][i] + bcv[0], 0.f);
        val += a4.y * fmaxf(acc[mt][1][i] + bcv[1], 0.f);
        val += a4.z * fmaxf(acc[mt][2][i] + bcv[2], 0.f);
        val += a4.w * fmaxf(acc[mt][3][i] + bcv[3], 0.f);
        out[(size_t)n * PC + d] = fmaxf(val, 0.f);
      }
    }
  }
}

extern "C" void kernel_launch(void* const* d_in, const int* in_sizes, int n_in,
                              void* d_out, int out_size, void* d_ws, size_t ws_size,
                              hipStream_t stream)
{
  const float* xf     = (const float*)d_in[0];
  const int* nbr_idx  = (const int*)d_in[1];
  const int* nbr_mask = (const int*)d_in[2];
  const int* coords   = (const int*)d_in[3];
  const float* Wt     = (const float*)d_in[4];
  const float* bt     = (const float*)d_in[5];
  const float* Wd     = (const float*)d_in[6];
  const float* bd     = (const float*)d_in[7];
  const float* Wpos   = (const float*)d_in[8];
  const float* bpos   = (const float*)d_in[9];
  const float* Wq     = (const float*)d_in[10];
  const float* bq     = (const float*)d_in[11];
  const float* proj   = (const float*)d_in[12];
  const float* Wv     = (const float*)d_in[13];
  const float* bv     = (const float*)d_in[14];
  const float* Wcode  = (const float*)d_in[15];
  const float* bcode  = (const float*)d_in[16];
  float* out = (float*)d_out;

  int N = in_sizes[0] / INC;

  char* ws = (char*)d_ws;
  size_t off = 0;
  auto alloc = [&](size_t bytes) {
    off = (off + 255) & ~(size_t)255;
    void* p = ws + off;
    off += bytes;
    return p;
  };
  ushort* v_ws  = (ushort*)alloc((size_t)N * PC * 2);
  ushort* zc_ws = (ushort*)alloc((size_t)N * 32 * 2);
  float*  a_ws  = (float*)alloc((size_t)N * 4 * 4);
  ushort* B_ws  = (ushort*)alloc((size_t)54 * 4 * 256 * 8 * 2);
  ushort* D_ws  = (ushort*)alloc((size_t)2048 * 2);
  (void)ws_size;

  hipLaunchKernelGGL(k_prepBD, dim3(1736), dim3(256), 0, stream,
                     Wcode, Wd, B_ws, D_ws);
  hipLaunchKernelGGL(k_prep, dim3((N + 15) / 16), dim3(256), 0, stream,
                     xf, Wt, bt, Wv, bv, Wq, coords, v_ws, zc_ws, N);
  hipLaunchKernelGGL(k_attn2, dim3((N + 7) / 8), dim3(256), 0, stream,
                     nbr_idx, nbr_mask, zc_ws, Wpos, bpos, Wq, bq, proj, a_ws, N);
  hipLaunchKernelGGL(k_code, dim3((N + 63) / 64), dim3(256), 0, stream,
                     v_ws, nbr_idx, nbr_mask, B_ws, a_ws, xf, D_ws, bd, bcode, out, N);
}

// Round 16
// 186.095 us; speedup vs baseline: 2.1698x; 1.6104x over previous
//
#include <hip/hip_runtime.h>

#define KK 27
#define INC 32
#define PC 64

typedef __attribute__((ext_vector_type(8))) short v8s;
typedef __attribute__((ext_vector_type(4))) float f32x4;

static __device__ __forceinline__ float b2f(ushort u) {
  union { float f; unsigned int i; } x; x.i = ((unsigned int)u) << 16; return x.f;
}
static __device__ __forceinline__ ushort f2b(float f) {
  union { float f; unsigned int i; } x; x.f = f;
  unsigned int u = x.i;
  unsigned int r = (u + 0x7FFFu + ((u >> 16) & 1u)) >> 16;
  return (ushort)r;
}

// ---------------- Kernel 1 (R16): MFMA-based prep. 64 voxels/block, 4 waves.
// Phase1: x=relu(xf@Wt+bt) -> xb LDS bf16. Phase2: v=relu(x@Wv+bv) -> global.
// Phase3: z[n][k]=dot(x,Wq_k) -> zc16 (+packed coords).
__global__ __launch_bounds__(256) void k_prep2(
    const float* __restrict__ xf, const ushort* __restrict__ Wtp, const float* __restrict__ bt,
    const ushort* __restrict__ Wvp, const float* __restrict__ bv,
    const ushort* __restrict__ Wqp, const int* __restrict__ coords,
    ushort* __restrict__ v, ushort* __restrict__ zc16, int N)
{
  const int tid = threadIdx.x;
  const int lane = tid & 63, w = tid >> 6;
  const int ln = lane & 15, grp = lane >> 4;
  const int base = blockIdx.x * 64;

  __shared__ __align__(16) ushort xfb[64][40];   // xf bf16, K=32 (pad 40)
  __shared__ __align__(16) ushort xb[64][72];    // x bf16, K=64 (pad 72)

  // stage xf -> bf16 LDS: 4 threads/row, 8 ch each
  {
    int r = tid >> 2, c0 = (tid & 3) * 8;
    int n = base + r;
    v8s d = {0,0,0,0,0,0,0,0};
    if (n < N) {
      float4 f0 = *(const float4*)(xf + (size_t)n * INC + c0);
      float4 f1 = *(const float4*)(xf + (size_t)n * INC + c0 + 4);
      d[0] = (short)f2b(f0.x); d[1] = (short)f2b(f0.y);
      d[2] = (short)f2b(f0.z); d[3] = (short)f2b(f0.w);
      d[4] = (short)f2b(f1.x); d[5] = (short)f2b(f1.y);
      d[6] = (short)f2b(f1.z); d[7] = (short)f2b(f1.w);
    }
    *(v8s*)(&xfb[r][c0]) = d;
  }
  // packed coords (independent of LDS)
  if (tid < 64) {
    int n = base + tid;
    if (n < N) {
      ushort* row = zc16 + (size_t)n * 32;
      row[0] = (ushort)coords[n * 3 + 0];
      row[1] = (ushort)coords[n * 3 + 1];
      row[2] = (ushort)coords[n * 3 + 2];
      row[3] = 0;
    }
  }
  __syncthreads();

  const int d = w * 16 + ln;
  // ---- phase 1: x = relu(xf@Wt+bt); wave w covers d-cols w*16..+15
  {
    v8s wtf = *(const v8s*)(Wtp + (size_t)d * 32 + grp * 8);
    float btv = bt[d];
    #pragma unroll
    for (int mt = 0; mt < 4; ++mt) {
      v8s af = *(const v8s*)(&xfb[mt * 16 + ln][grp * 8]);
      f32x4 z4 = {0.f, 0.f, 0.f, 0.f};
      f32x4 acc = __builtin_amdgcn_mfma_f32_16x16x32_bf16(af, wtf, z4, 0, 0, 0);
      #pragma unroll
      for (int i = 0; i < 4; ++i) {
        int row = mt * 16 + grp * 4 + i;
        xb[row][d] = f2b(fmaxf(acc[i] + btv, 0.f));
      }
    }
  }
  __syncthreads();

  // ---- phase 2: v = relu(x@Wv+bv); K=64 in 2 chunks
  {
    v8s wv0 = *(const v8s*)(Wvp + (size_t)d * 64 + grp * 8);
    v8s wv1 = *(const v8s*)(Wvp + (size_t)d * 64 + 32 + grp * 8);
    float bvv = bv[d];
    #pragma unroll
    for (int mt = 0; mt < 4; ++mt) {
      v8s a0 = *(const v8s*)(&xb[mt * 16 + ln][grp * 8]);
      v8s a1 = *(const v8s*)(&xb[mt * 16 + ln][32 + grp * 8]);
      f32x4 acc = {0.f, 0.f, 0.f, 0.f};
      acc = __builtin_amdgcn_mfma_f32_16x16x32_bf16(a0, wv0, acc, 0, 0, 0);
      acc = __builtin_amdgcn_mfma_f32_16x16x32_bf16(a1, wv1, acc, 0, 0, 0);
      #pragma unroll
      for (int i = 0; i < 4; ++i) {
        int row = mt * 16 + grp * 4 + i;
        int n = base + row;
        if (n < N) v[(size_t)n * PC + d] = f2b(fmaxf(acc[i] + bvv, 0.f));
      }
    }
  }

  // ---- phase 3: z = x@Wq^T; cols = k (27 pad 32). wave w: col-tile w&1,
  // row-tiles mt = 2*(w>>1)+{0,1}
  {
    const int kcol = (w & 1) * 16 + ln;
    v8s wq0 = *(const v8s*)(Wqp + (size_t)kcol * 64 + grp * 8);
    v8s wq1 = *(const v8s*)(Wqp + (size_t)kcol * 64 + 32 + grp * 8);
    #pragma unroll
    for (int mtt = 0; mtt < 2; ++mtt) {
      int mt = 2 * (w >> 1) + mtt;
      v8s a0 = *(const v8s*)(&xb[mt * 16 + ln][grp * 8]);
      v8s a1 = *(const v8s*)(&xb[mt * 16 + ln][32 + grp * 8]);
      f32x4 acc = {0.f, 0.f, 0.f, 0.f};
      acc = __builtin_amdgcn_mfma_f32_16x16x32_bf16(a0, wq0, acc, 0, 0, 0);
      acc = __builtin_amdgcn_mfma_f32_16x16x32_bf16(a1, wq1, acc, 0, 0, 0);
      if (kcol < KK) {
        #pragma unroll
        for (int i = 0; i < 4; ++i) {
          int row = mt * 16 + grp * 4 + i;
          int n = base + row;
          if (n < N) zc16[(size_t)n * 32 + 4 + kcol] = f2b(acc[i]);
        }
      }
    }
  }
}

// ---------------- Kernel 2: repack W_code->Bp, Wd->Wdp, Wt->Wtp, Wv->Wvp, Wq->Wqp
__global__ __launch_bounds__(256) void k_prepBD(
    const float* __restrict__ Wcode, const float* __restrict__ Wd,
    const float* __restrict__ Wt, const float* __restrict__ Wv, const float* __restrict__ Wq,
    ushort* __restrict__ Bp, ushort* __restrict__ Wdp,
    ushort* __restrict__ Wtp, ushort* __restrict__ Wvp, ushort* __restrict__ Wqp)
{
  int bid = blockIdx.x;
  if (bid < 1728) {
    int i = bid * 256 + threadIdx.x;   // 442368
    int j = i & 7;
    int col = (i >> 3) & 255;
    int kg = (i >> 11) & 3;
    int s = i >> 13;
    int k = s * 32 + kg * 8 + j;
    int m = col >> 6, dd = col & 63;
    int knbr = k >> 6, c = k & 63;
    Bp[i] = f2b(Wcode[(((m * KK + knbr) * 64) + c) * 64 + dd]);
  } else if (bid < 1736) {
    int i = (bid - 1728) * 256 + threadIdx.x;   // 2048: Wdp[d][k]
    int col = i >> 5, k = i & 31;
    Wdp[i] = f2b(Wd[k * PC + col]);
  } else if (bid < 1744) {
    int i = (bid - 1736) * 256 + threadIdx.x;   // 2048: Wtp[d][k], k=32
    int col = i >> 5, k = i & 31;
    Wtp[i] = f2b(Wt[k * PC + col]);
  } else if (bid < 1760) {
    int i = (bid - 1744) * 256 + threadIdx.x;   // 4096: Wvp[d][k], k=64
    int col = i >> 6, k = i & 63;
    Wvp[i] = f2b(Wv[k * PC + col]);
  } else {
    int i = (bid - 1760) * 256 + threadIdx.x;   // 2048: Wqp[kcol][c], kcol=32 pad
    int kcol = i >> 6, c = i & 63;
    Wqp[i] = (kcol < KK) ? f2b(Wq[kcol * PC + c]) : (ushort)0;
  }
}

// ---------------- Kernel 3: PARALLEL-k attention (R14, unchanged)
__global__ __launch_bounds__(256) void k_attn2(
    const int* __restrict__ nbr_idx, const int* __restrict__ nbr_mask,
    const ushort* __restrict__ zc16,
    const float* __restrict__ Wpos, const float* __restrict__ bpos,
    const float* __restrict__ Wq, const float* __restrict__ bq,
    const float* __restrict__ proj, float* __restrict__ attn, int N)
{
  int tid = threadIdx.x;
  int wv = tid >> 6, lane = tid & 63;
  int half = lane >> 5, l = lane & 31;
  int n = blockIdx.x * 8 + wv * 2 + half;
  bool vok = (n < N);
  int j = -1;
  if (vok && l < KK) {
    if (nbr_mask[(size_t)n * KK + l]) j = nbr_idx[(size_t)n * KK + l];
  }
  int cx = 0, cy = 0, cz = 0;
  if (vok) {
    uint2 cd = *(const uint2*)(zc16 + (size_t)n * 32);
    cx = (int)(cd.x & 0xffffu); cy = (int)(cd.x >> 16); cz = (int)(cd.y & 0xffffu);
  }
  float qc = 0.f;
  if (j >= 0) {
    uint2 cj = *(const uint2*)(zc16 + (size_t)j * 32);
    float z = b2f(zc16[(size_t)j * 32 + 4 + l]);
    float rx = (float)((int)(cj.x & 0xffffu) - cx);
    float ry = (float)((int)(cj.x >> 16) - cy);
    float rz = (float)((int)(cj.y & 0xffffu) - cz);
    float t = 0.f;
    #pragma unroll
    for (int c4 = 0; c4 < 16; ++c4) {
      float4 w0 = *(const float4*)(Wpos + c4 * 4);
      float4 w1 = *(const float4*)(Wpos + 64 + c4 * 4);
      float4 w2 = *(const float4*)(Wpos + 128 + c4 * 4);
      float4 bp = *(const float4*)(bpos + c4 * 4);
      float4 wq = *(const float4*)(Wq + (size_t)l * PC + c4 * 4);
      t += fmaxf(rx * w0.x + ry * w1.x + rz * w2.x + bp.x, 0.f) * wq.x;
      t += fmaxf(rx * w0.y + ry * w1.y + rz * w2.y + bp.y, 0.f) * wq.y;
      t += fmaxf(rx * w0.z + ry * w1.z + rz * w2.z + bp.z, 0.f) * wq.z;
      t += fmaxf(rx * w0.w + ry * w1.w + rz * w2.w + bp.w, 0.f) * wq.w;
    }
    qc = z + t;
  }
  qc += __shfl_xor(qc, 1); qc += __shfl_xor(qc, 2); qc += __shfl_xor(qc, 4);
  qc += __shfl_xor(qc, 8); qc += __shfl_xor(qc, 16);
  if (vok && l == 0) {
    float q = fmaxf(qc + bq[0], 0.f);
    float lg[4], mx = -1e30f;
    #pragma unroll
    for (int m = 0; m < 4; ++m) { lg[m] = q * proj[m] * 0.1f; mx = fmaxf(mx, lg[m]); }
    float s = 0.f;
    #pragma unroll
    for (int m = 0; m < 4; ++m) { lg[m] = __expf(lg[m] - mx); s += lg[m]; }
    float inv = 1.f / s;
    #pragma unroll
    for (int m = 0; m < 4; ++m) attn[(size_t)n * 4 + m] = lg[m] * inv;
  }
}

// ---------------- Kernel 4: gathered GEMM — R9 core verbatim (unchanged)
__global__ __launch_bounds__(256) void k_code(
    const ushort* __restrict__ v, const int* __restrict__ nbr_idx, const int* __restrict__ nbr_mask,
    const ushort* __restrict__ Bp, const float* __restrict__ attn,
    const float* __restrict__ xf, const ushort* __restrict__ Wdp, const float* __restrict__ bd,
    const float* __restrict__ bcode, float* __restrict__ out, int N)
{
  const int tid = threadIdx.x;
  const int lane = tid & 63, w = tid >> 6;
  const int base = blockIdx.x * 64;

  __shared__ __align__(16) union SM {
    struct { ushort As[3][4096]; int jm[64][KK]; } g;   // GEMM phase (31.5 KB)
    struct { ushort xfb[64][40]; } e;                   // epilogue (5.1 KB)
  } sm;

  for (int i = tid; i < 64 * KK; i += 256) {
    int r = i / KK, k = i % KK;
    int n = base + r;
    int val = -1;
    if (n < N && nbr_mask[(size_t)n * KK + k]) val = nbr_idx[(size_t)n * KK + k];
    sm.g.jm[r][k] = val;
  }

  const int r0 = tid >> 3, cc0 = tid & 7;
  const int r1 = r0 + 32,  cc1 = cc0;
  const int sc0 = cc0 ^ (r0 & 7), sc1 = cc1 ^ (r1 & 7);

  __syncthreads();  // jm ready

  uint4 R0 = make_uint4(0u,0u,0u,0u), R1 = R0;
  {
    int j0 = sm.g.jm[r0][0], j1 = sm.g.jm[r1][0];
    uint4 p0 = make_uint4(0u, 0u, 0u, 0u), p1 = p0;
    if (j0 >= 0) p0 = *(const uint4*)(v + (size_t)j0 * PC + cc0 * 8);
    if (j1 >= 0) p1 = *(const uint4*)(v + (size_t)j1 * PC + cc1 * 8);
    int jc = sm.g.jm[r0][1], jd = sm.g.jm[r1][1];
    if (jc >= 0) R0 = *(const uint4*)(v + (size_t)jc * PC + cc0 * 8);
    if (jd >= 0) R1 = *(const uint4*)(v + (size_t)jd * PC + cc1 * 8);
    *(uint4*)(&sm.g.As[0][r0 * 64 + sc0 * 8]) = p0;
    *(uint4*)(&sm.g.As[0][r1 * 64 + sc1 * 8]) = p1;
  }
  __syncthreads();

  f32x4 acc[4][4] = {};
  const ushort* bbase = Bp + (size_t)(lane >> 4) * 2048 + (size_t)((w << 4) + (lane & 15)) * 8;

  int cur = 0, nx = 1;
  for (int kn = 0; kn < KK; ++kn) {
    v8s bf0[4], bf1[4];
    {
      const ushort* bb0 = bbase + (size_t)(8 * kn) * 2048;
      const ushort* bb1 = bb0 + 4 * 2048;
      #pragma unroll
      for (int nt = 0; nt < 4; ++nt) {
        bf0[nt] = *(const v8s*)(bb0 + nt * 512);
        bf1[nt] = *(const v8s*)(bb1 + nt * 512);
      }
    }
    if (kn + 1 < KK) {
      *(uint4*)(&sm.g.As[nx][r0 * 64 + sc0 * 8]) = R0;
      *(uint4*)(&sm.g.As[nx][r1 * 64 + sc1 * 8]) = R1;
    }
    R0 = make_uint4(0u,0u,0u,0u); R1 = R0;
    if (kn + 2 < KK) {
      int j0 = sm.g.jm[r0][kn + 2], j1 = sm.g.jm[r1][kn + 2];
      if (j0 >= 0) R0 = *(const uint4*)(v + (size_t)j0 * PC + cc0 * 8);
      if (j1 >= 0) R1 = *(const uint4*)(v + (size_t)j1 * PC + cc1 * 8);
    }
    #pragma unroll
    for (int s2 = 0; s2 < 2; ++s2) {
      v8s af[4];
      const int cc = s2 * 4 + (lane >> 4);
      #pragma unroll
      for (int mt = 0; mt < 4; ++mt) {
        const int r = mt * 16 + (lane & 15);
        const int sc = cc ^ (r & 7);
        af[mt] = *(const v8s*)(&sm.g.As[cur][r * 64 + sc * 8]);
      }
      #pragma unroll
      for (int mt = 0; mt < 4; ++mt)
        #pragma unroll
        for (int nt = 0; nt < 4; ++nt)
          acc[mt][nt] = __builtin_amdgcn_mfma_f32_16x16x32_bf16(
              af[mt], (s2 ? bf1[nt] : bf0[nt]), acc[mt][nt], 0, 0, 0);
    }
    __syncthreads();
    cur = nx; nx = (nx == 2) ? 0 : nx + 1;
  }

  for (int i2 = tid; i2 < 2048; i2 += 256) {
    int r = i2 >> 5, c = i2 & 31;
    int n = base + r;
    sm.e.xfb[r][c] = (n < N) ? f2b(xf[(size_t)n * INC + c]) : (ushort)0;
  }
  __syncthreads();

  const int ln = lane & 15, grp = lane >> 4;
  const int d = (w << 4) + ln;
  v8s wdf = *(const v8s*)(Wdp + (size_t)d * 32 + grp * 8);
  f32x4 res[4];
  #pragma unroll
  for (int mt = 0; mt < 4; ++mt) {
    v8s af = *(const v8s*)(&sm.e.xfb[mt * 16 + ln][grp * 8]);
    f32x4 z = {0.f, 0.f, 0.f, 0.f};
    res[mt] = __builtin_amdgcn_mfma_f32_16x16x32_bf16(af, wdf, z, 0, 0, 0);
  }
  float bcv[4];
  #pragma unroll
  for (int nt = 0; nt < 4; ++nt) bcv[nt] = bcode[nt * PC + d];
  const float bdv = bd[d];
  #pragma unroll
  for (int mt = 0; mt < 4; ++mt) {
    #pragma unroll
    for (int i = 0; i < 4; ++i) {
      int row = mt * 16 + grp * 4 + i;
      int n = base + row;
      if (n < N) {
        float4 a4 = *(const float4*)(attn + (size_t)n * 4);
        float val = res[mt][i] + bdv;
        val += a4.x * fmaxf(acc[mt][0][i] + bcv[0], 0.f);
        val += a4.y * fmaxf(acc[mt][1][i] + bcv[1], 0.f);
        val += a4.z * fmaxf(acc[mt][2][i] + bcv[2], 0.f);
        val += a4.w * fmaxf(acc[mt][3][i] + bcv[3], 0.f);
        out[(size_t)n * PC + d] = fmaxf(val, 0.f);
      }
    }
  }
}

extern "C" void kernel_launch(void* const* d_in, const int* in_sizes, int n_in,
                              void* d_out, int out_size, void* d_ws, size_t ws_size,
                              hipStream_t stream)
{
  const float* xf     = (const float*)d_in[0];
  const int* nbr_idx  = (const int*)d_in[1];
  const int* nbr_mask = (const int*)d_in[2];
  const int* coords   = (const int*)d_in[3];
  const float* Wt     = (const float*)d_in[4];
  const float* bt     = (const float*)d_in[5];
  const float* Wd     = (const float*)d_in[6];
  const float* bd     = (const float*)d_in[7];
  const float* Wpos   = (const float*)d_in[8];
  const float* bpos   = (const float*)d_in[9];
  const float* Wq     = (const float*)d_in[10];
  const float* bq     = (const float*)d_in[11];
  const float* proj   = (const float*)d_in[12];
  const float* Wv     = (const float*)d_in[13];
  const float* bv     = (const float*)d_in[14];
  const float* Wcode  = (const float*)d_in[15];
  const float* bcode  = (const float*)d_in[16];
  float* out = (float*)d_out;

  int N = in_sizes[0] / INC;

  char* ws = (char*)d_ws;
  size_t off = 0;
  auto alloc = [&](size_t bytes) {
    off = (off + 255) & ~(size_t)255;
    void* p = ws + off;
    off += bytes;
    return p;
  };
  ushort* v_ws  = (ushort*)alloc((size_t)N * PC * 2);
  ushort* zc_ws = (ushort*)alloc((size_t)N * 32 * 2);
  float*  a_ws  = (float*)alloc((size_t)N * 4 * 4);
  ushort* B_ws  = (ushort*)alloc((size_t)54 * 4 * 256 * 8 * 2);
  ushort* D_ws  = (ushort*)alloc((size_t)2048 * 2);
  ushort* T_ws  = (ushort*)alloc((size_t)2048 * 2);
  ushort* V2_ws = (ushort*)alloc((size_t)4096 * 2);
  ushort* Q_ws  = (ushort*)alloc((size_t)2048 * 2);
  (void)ws_size;

  hipLaunchKernelGGL(k_prepBD, dim3(1768), dim3(256), 0, stream,
                     Wcode, Wd, Wt, Wv, Wq, B_ws, D_ws, T_ws, V2_ws, Q_ws);
  hipLaunchKernelGGL(k_prep2, dim3((N + 63) / 64), dim3(256), 0, stream,
                     xf, T_ws, bt, V2_ws, bv, Q_ws, coords, v_ws, zc_ws, N);
  hipLaunchKernelGGL(k_attn2, dim3((N + 7) / 8), dim3(256), 0, stream,
                     nbr_idx, nbr_mask, zc_ws, Wpos, bpos, Wq, bq, proj, a_ws, N);
  hipLaunchKernelGGL(k_code, dim3((N + 63) / 64), dim3(256), 0, stream,
                     v_ws, nbr_idx, nbr_mask, B_ws, a_ws, xf, D_ws, bd, bcode, out, N);
}